// Round 3
// baseline (193.314 us; speedup 1.0000x reference)
//
#include <hip/hip_runtime.h>
#include <hip/hip_bf16.h>
#include <cmath>
#include <cstddef>

#define N 8192
#define D 256
#define BI 128
#define NT (N / BI)        // 64 row tiles
#define NTRI (NT * (NT + 1) / 2)   // 2080 upper-triangle tiles (= 8 * 260)

typedef __attribute__((ext_vector_type(8))) short short8;   // 8 bf16 = one MFMA A/B frag
typedef __attribute__((ext_vector_type(4))) float float4v;  // MFMA C/D frag

__device__ inline ushort f2bf(float x) {
    __hip_bfloat16 h = __float2bfloat16(x);
    return __builtin_bit_cast(ushort, h);
}
__device__ inline float bf2f(ushort u) {
    __hip_bfloat16 h = __builtin_bit_cast(__hip_bfloat16, u);
    return __bfloat162float(h);
}

// sortable pack: (monotone-uint(key) << 32) | idx  -> atomicMin == argmin, lowest-idx tie-break
__device__ inline unsigned long long packKI(float k, int idx) {
    unsigned u = __float_as_uint(k);
    u = (u & 0x80000000u) ? ~u : (u | 0x80000000u);
    return ((unsigned long long)u << 32) | (unsigned)idx;
}

// T(t) = pairs before row t in row-major upper triangle (incl. diagonal), NT=64
__device__ inline int triT(int t) { return t * (129 - t) / 2; }

// ============================================================================
// Frag-tiled bf16 layout: the MFMA A/B fragment for (16-row group r16, k-chunk
// ktc, lane) lives at ushort offset (r16*8 + ktc)*512 + lane*8, so a wave's
// frag load is wave-uniform base + lane*16B: one coalesced 1 KB dwordx4.
// ============================================================================

// load one k-chunk's 16 frags (A hi/lo rt=0..3, B hi/lo ct=0..3) into registers.
// All 16 issued back-to-back; caller fences with sched_barrier so they cannot
// be re-sunk into the MFMA cluster (forces ~16 outstanding vmem ops).
__device__ __forceinline__ void loadk(const ushort* __restrict__ Ehi, const ushort* __restrict__ Elo,
                                      int pA, int pB, int lo8, int ktc,
                                      short8 (&ah)[4], short8 (&al)[4],
                                      short8 (&bh)[4], short8 (&bl)[4]) {
    #pragma unroll
    for (int rt = 0; rt < 4; rt++) {
        const int o = ((pA + rt) * 8 + ktc) * 512 + lo8;
        ah[rt] = *(const short8*)&Ehi[o];
        al[rt] = *(const short8*)&Elo[o];
    }
    #pragma unroll
    for (int ct = 0; ct < 4; ct++) {
        const int o = ((pB + ct) * 8 + ktc) * 512 + lo8;
        bh[ct] = *(const short8*)&Ehi[o];
        bl[ct] = *(const short8*)&Elo[o];
    }
}

// 48 MFMAs for one k-chunk. Pass-outer order (16 independent MFMAs between
// dependent ones); per-acc accumulation order (hh,hl,lh) identical to all
// prior revs -> bit-identical keys -> identical argmin indices.
__device__ __forceinline__ void mfmak(const short8 (&ah)[4], const short8 (&al)[4],
                                      const short8 (&bh)[4], const short8 (&bl)[4],
                                      float4v (&acc)[4][4]) {
    #pragma unroll
    for (int rt = 0; rt < 4; rt++)
        #pragma unroll
        for (int ct = 0; ct < 4; ct++)
            acc[rt][ct] = __builtin_amdgcn_mfma_f32_16x16x32_bf16(ah[rt], bh[ct], acc[rt][ct], 0, 0, 0);
    #pragma unroll
    for (int rt = 0; rt < 4; rt++)
        #pragma unroll
        for (int ct = 0; ct < 4; ct++)
            acc[rt][ct] = __builtin_amdgcn_mfma_f32_16x16x32_bf16(ah[rt], bl[ct], acc[rt][ct], 0, 0, 0);
    #pragma unroll
    for (int rt = 0; rt < 4; rt++)
        #pragma unroll
        for (int ct = 0; ct < 4; ct++)
            acc[rt][ct] = __builtin_amdgcn_mfma_f32_16x16x32_bf16(al[rt], bh[ct], acc[rt][ct], 0, 0, 0);
}

// ---------------- K1: fused prep — M init, copies, sqnorm, frag-tiled bf16 hi/lo split ----
// grid MUST be 1024 x 256 (phase C uses exactly 4096 waves, one 16x32 tile each).
__global__ void prep_kernel(const float4* __restrict__ a, const float4* __restrict__ p,
                            float4* __restrict__ out, float* __restrict__ sq,
                            ushort* __restrict__ Ehi, ushort* __restrict__ Elo,
                            unsigned long long* __restrict__ M) {
    const int gsz = gridDim.x * blockDim.x;          // 262144, multiple of 64
    const int g0 = blockIdx.x * blockDim.x + threadIdx.x;
    const int total = N * D / 4;                     // 524288 float4

    // phase A: e_actv copy + per-row sqnorm (one row per wave per iter: 64 float4 = 1 row)
    for (int idx = g0; idx < total; idx += gsz) {
        float4 v = a[idx];
        out[idx] = v;
        float s = v.x * v.x + v.y * v.y + v.z * v.z + v.w * v.w;
        #pragma unroll
        for (int off = 32; off; off >>= 1) s += __shfl_down(s, off);
        if ((threadIdx.x & 63) == 0) sq[idx >> 6] = s;
    }
    // phase B: e_ap plain copy into second output slot
    for (int idx = g0; idx < total; idx += gsz) out[total + idx] = p[idx];

    // phase C: frag-tiled hi/lo split. One wave per (r16, ktc) tile of 16 rows x 32 k.
    // Lane (q,tx) reads 8 floats of row r16*16+tx at k = ktc*32 + q*8, writes one
    // 16B frag at lane*16B -> coalesced 1KB stores. Same per-element arithmetic as
    // before -> bit-identical MFMA inputs.
    {
        const int w = g0 >> 6;           // global wave id, 0..4095
        if (w < 4096) {
            const int lane = threadIdx.x & 63;
            const int tx = lane & 15;
            const int q  = lane >> 4;
            const int r16 = w >> 3;      // 0..511
            const int ktc = w & 7;       // 0..7
            const int row = r16 * 16 + tx;
            const float4 v0 = a[row * 64 + ktc * 8 + q * 2];
            const float4 v1 = a[row * 64 + ktc * 8 + q * 2 + 1];
            float e[8] = {v0.x, v0.y, v0.z, v0.w, v1.x, v1.y, v1.z, v1.w};
            short8 hs, ls;
            #pragma unroll
            for (int j = 0; j < 8; j++) {
                ushort h = f2bf(e[j]);
                ushort l = f2bf(e[j] - bf2f(h));
                hs[j] = (short)h;
                ls[j] = (short)l;
            }
            const size_t off = (size_t)(r16 * 8 + ktc) * 512 + lane * 8;
            *(short8*)&Ehi[off] = hs;
            *(short8*)&Elo[off] = ls;
        }
    }
    // M init
    for (int i = g0; i < N; i += gsz) M[i] = 0xFFFFFFFFFFFFFFFFull;
}

// ---------------- K2: symmetric split-bf16 MFMA + dual-sided masked argmin ----------------
// Barrier-free K-loop, register-double-buffered and fenced: per chunk, all 16
// frag loads of the NEXT chunk issue back-to-back (16 vmem ops in flight),
// then sched_barrier(0), then the current chunk's 48 MFMAs. The fence stops
// the scheduler from re-sinking loads to their uses (which serialized round 2
// into ~600-cycle per-load stalls: VGPR_Count=80, ~73K cyc/block).
__launch_bounds__(256, 2)
__global__ void argmin_sym(const ushort* __restrict__ Ehi, const ushort* __restrict__ Elo,
                           const int* __restrict__ host, const float* __restrict__ sq,
                           unsigned long long* __restrict__ M) {
    // XCD swizzle then decode linear tile id -> (ti, tj), ti <= tj
    const int b0 = blockIdx.x;
    const int b = (b0 & 7) * (NTRI / 8) + (b0 >> 3);
    int ti = (int)floor(64.5 - sqrt(64.5 * 64.5 - 2.0 * (double)b));
    while (triT(ti + 1) <= b) ti++;
    while (triT(ti) > b) ti--;
    const int tj = ti + (b - triT(ti));

    __shared__ float sqA_s[BI], sqB_s[BI];
    __shared__ int   hostB_s[BI];
    __shared__ float rowV[2 * BI]; __shared__ int rowI[2 * BI];
    __shared__ float colV[2 * BI]; __shared__ int colI[2 * BI];

    const int ib0 = ti * BI;
    const int jb0 = tj * BI;
    const int tid = threadIdx.x;
    const int lane = tid & 63;
    const int wave = tid >> 6;      // 0..3
    const int wrow = wave >> 1;     // 0..1
    const int wcol = wave & 1;      // 0..1
    const int tx = lane & 15;       // 0..15
    const int q  = lane >> 4;       // 0..3

    // epilogue scalars (consumed only after the pre-epilogue barrier)
    if (tid < BI) {
        sqA_s[tid] = sq[ib0 + tid];
        sqB_s[tid] = sq[jb0 + tid];
        hostB_s[tid] = host[jb0 + tid];
    }

    // hostA packed per rt: 4 bytes = hosts of rows (rt,reg) for this lane (host < 64)
    unsigned hostAp[4];
    #pragma unroll
    for (int rt = 0; rt < 4; rt++) {
        unsigned p = 0;
        #pragma unroll
        for (int reg = 0; reg < 4; reg++) {
            int hv = host[ib0 + wrow * 64 + rt * 16 + q * 4 + reg];
            p |= ((unsigned)hv & 0xFFu) << (8 * reg);
        }
        hostAp[rt] = p;
    }

    float4v acc[4][4];   // [rt][ct]
    #pragma unroll
    for (int rt = 0; rt < 4; rt++)
        #pragma unroll
        for (int ct = 0; ct < 4; ct++) acc[rt][ct] = (float4v)(0.0f);

    // frag-tile row16 bases for this wave's A rows / B cols
    const int pA = (ib0 >> 4) + wrow * 4;   // + rt
    const int pB = (jb0 >> 4) + wcol * 4;   // + ct
    const int lo8 = lane * 8;

    // two named register sets (statically indexed everywhere -> no scratch)
    short8 ah0[4], al0[4], bh0[4], bl0[4];
    short8 ah1[4], al1[4], bh1[4], bl1[4];

    loadk(Ehi, Elo, pA, pB, lo8, 0, ah0, al0, bh0, bl0);
    #pragma unroll
    for (int kk = 0; kk < 4; kk++) {
        loadk(Ehi, Elo, pA, pB, lo8, 2 * kk + 1, ah1, al1, bh1, bl1);
        __builtin_amdgcn_sched_barrier(0);
        mfmak(ah0, al0, bh0, bl0, acc);
        if (kk < 3) loadk(Ehi, Elo, pA, pB, lo8, 2 * kk + 2, ah0, al0, bh0, bl0);
        __builtin_amdgcn_sched_barrier(0);
        mfmak(ah1, al1, bh1, bl1, acc);
    }

    // ---- epilogue: dual-sided argmin ----
    __syncthreads();   // orders the tid<128 sq/host staging before reads (only block barrier)

    // rows side: for each of this lane's 16 rows, min over its 4 ct entries, then over tx
    #pragma unroll
    for (int rt = 0; rt < 4; rt++) {
        unsigned hp = hostAp[rt];
        #pragma unroll
        for (int reg = 0; reg < 4; reg++) {
            int il = wrow * 64 + rt * 16 + q * 4 + reg;
            int ig = ib0 + il;
            int ha = (int)((hp >> (8 * reg)) & 0xFFu);
            float v = 3.0e38f; int ix = 0x7fffffff;
            #pragma unroll
            for (int ct = 0; ct < 4; ct++) {
                int jl = wcol * 64 + ct * 16 + tx;
                int jg = jb0 + jl;
                float key = sqB_s[jl] - 2.0f * acc[rt][ct][reg];
                bool masked = (hostB_s[jl] == ha) || (jg == ig);
                if (!masked && (key < v || (key == v && jg < ix))) { v = key; ix = jg; }
            }
            #pragma unroll
            for (int d = 1; d < 16; d <<= 1) {
                float ov = __shfl_xor(v, d);
                int   oi = __shfl_xor(ix, d);
                if (ov < v || (ov == v && oi < ix)) { v = ov; ix = oi; }
            }
            if (tx == 0) { rowV[il * 2 + wcol] = v; rowI[il * 2 + wcol] = ix; }
        }
    }

    // cols side (off-diagonal only): per lane's 4 cols, min over 16 row entries, then over q
    if (ti != tj) {
        #pragma unroll
        for (int ct = 0; ct < 4; ct++) {
            int jl = wcol * 64 + ct * 16 + tx;
            int hb = hostB_s[jl];
            float v = 3.0e38f; int ix = 0x7fffffff;
            #pragma unroll
            for (int rt = 0; rt < 4; rt++) {
                unsigned hp = hostAp[rt];
                #pragma unroll
                for (int reg = 0; reg < 4; reg++) {
                    int il = wrow * 64 + rt * 16 + q * 4 + reg;
                    int ig = ib0 + il;
                    bool masked = ((int)((hp >> (8 * reg)) & 0xFFu) == hb);
                    float key = sqA_s[il] - 2.0f * acc[rt][ct][reg];
                    if (!masked && (key < v || (key == v && ig < ix))) { v = key; ix = ig; }
                }
            }
            #pragma unroll
            for (int d = 16; d < 64; d <<= 1) {
                float ov = __shfl_xor(v, d);
                int   oi = __shfl_xor(ix, d);
                if (ov < v || (ov == v && oi < ix)) { v = ov; ix = oi; }
            }
            if (q == 0) { colV[jl * 2 + wrow] = v; colI[jl * 2 + wrow] = ix; }
        }
    }

    __syncthreads();
    if (tid < BI) {
        float v0 = rowV[tid * 2];     int x0 = rowI[tid * 2];
        float v1 = rowV[tid * 2 + 1]; int x1 = rowI[tid * 2 + 1];
        if (v1 < v0 || (v1 == v0 && x1 < x0)) { v0 = v1; x0 = x1; }
        atomicMin(&M[ib0 + tid], packKI(v0, x0));
        if (ti != tj) {
            float w0 = colV[tid * 2];     int y0 = colI[tid * 2];
            float w1 = colV[tid * 2 + 1]; int y1 = colI[tid * 2 + 1];
            if (w1 < w0 || (w1 == w0 && y1 < y0)) { w0 = w1; y0 = y1; }
            atomicMin(&M[jb0 + tid], packKI(w0, y0));
        }
    }
}

// ---------------- K3: extract index and gather e_an rows ----------------
__global__ void finalize_kernel(const unsigned long long* __restrict__ M,
                                const float* __restrict__ E, float* __restrict__ out_an) {
    int row = blockIdx.x;
    int t = threadIdx.x;   // 64
    int idx = (int)(unsigned)(M[row] & 0xFFFFFFFFull);
    float4 v = *(const float4*)&E[(size_t)idx * D + t * 4];
    *(float4*)&out_an[(size_t)row * D + t * 4] = v;
}

extern "C" void kernel_launch(void* const* d_in, const int* in_sizes, int n_in,
                              void* d_out, int out_size, void* d_ws, size_t ws_size,
                              hipStream_t stream) {
    const float* e_actv = (const float*)d_in[0];
    const float* e_ap   = (const float*)d_in[1];
    const int*   host   = (const int*)d_in[2];
    float* out = (float*)d_out;

    // workspace: M u64[N] | sq f32[N] | Ehi bf16[N*D] | Elo bf16[N*D]  (~8.3 MB)
    unsigned long long* M = (unsigned long long*)d_ws;
    float*  sq  = (float*)(M + N);
    ushort* Ehi = (ushort*)(sq + N);
    ushort* Elo = Ehi + (size_t)N * D;

    prep_kernel<<<1024, 256, 0, stream>>>(
        (const float4*)e_actv, (const float4*)e_ap, (float4*)out,
        sq, Ehi, Elo, M);
    argmin_sym<<<NTRI, 256, 0, stream>>>(Ehi, Elo, host, sq, M);
    finalize_kernel<<<N, 64, 0, stream>>>(M, e_actv, out + 2 * (size_t)N * D);
}

// Round 4
// 188.029 us; speedup vs baseline: 1.0281x; 1.0281x over previous
//
#include <hip/hip_runtime.h>
#include <hip/hip_bf16.h>
#include <cmath>
#include <cstddef>

#define N 8192
#define D 256
#define BI 128
#define NT (N / BI)        // 64 row tiles
#define NTRI (NT * (NT + 1) / 2)   // 2080 upper-triangle tiles (= 8 * 260)

typedef __attribute__((ext_vector_type(8))) short short8;   // 8 bf16 = one MFMA A/B frag
typedef __attribute__((ext_vector_type(4))) float float4v;  // MFMA C/D frag

__device__ inline ushort f2bf(float x) {
    __hip_bfloat16 h = __float2bfloat16(x);
    return __builtin_bit_cast(ushort, h);
}
__device__ inline float bf2f(ushort u) {
    __hip_bfloat16 h = __builtin_bit_cast(__hip_bfloat16, u);
    return __bfloat162float(h);
}

// sortable pack: (monotone-uint(key) << 32) | idx  -> atomicMin == argmin, lowest-idx tie-break
__device__ inline unsigned long long packKI(float k, int idx) {
    unsigned u = __float_as_uint(k);
    u = (u & 0x80000000u) ? ~u : (u | 0x80000000u);
    return ((unsigned long long)u << 32) | (unsigned)idx;
}

// T(t) = pairs before row t in row-major upper triangle (incl. diagonal), NT=64
__device__ inline int triT(int t) { return t * (129 - t) / 2; }

// ============================================================================
// Frag-tiled bf16 layout: the MFMA A/B fragment for (16-row group r16, k-chunk
// ktc, lane) lives at ushort offset (r16*8 + ktc)*512 + lane*8, so a wave's
// frag load is wave-uniform base + lane*16B: one coalesced 1 KB dwordx4.
// ============================================================================

// ---------------- K1: fused prep — M init, copies, sqnorm, frag-tiled bf16 hi/lo split ----
// grid MUST be 1024 x 256 (phase C uses exactly 4096 waves, one 16x32 tile each).
__global__ void prep_kernel(const float4* __restrict__ a, const float4* __restrict__ p,
                            float4* __restrict__ out, float* __restrict__ sq,
                            ushort* __restrict__ Ehi, ushort* __restrict__ Elo,
                            unsigned long long* __restrict__ M) {
    const int gsz = gridDim.x * blockDim.x;          // 262144, multiple of 64
    const int g0 = blockIdx.x * blockDim.x + threadIdx.x;
    const int total = N * D / 4;                     // 524288 float4

    // phase A: e_actv copy + per-row sqnorm (one row per wave per iter: 64 float4 = 1 row)
    for (int idx = g0; idx < total; idx += gsz) {
        float4 v = a[idx];
        out[idx] = v;
        float s = v.x * v.x + v.y * v.y + v.z * v.z + v.w * v.w;
        #pragma unroll
        for (int off = 32; off; off >>= 1) s += __shfl_down(s, off);
        if ((threadIdx.x & 63) == 0) sq[idx >> 6] = s;
    }
    // phase B: e_ap plain copy into second output slot
    for (int idx = g0; idx < total; idx += gsz) out[total + idx] = p[idx];

    // phase C: frag-tiled hi/lo split. One wave per (r16, ktc) tile of 16 rows x 32 k.
    // Lane (q,tx) reads 8 floats of row r16*16+tx at k = ktc*32 + q*8, writes one
    // 16B frag at lane*16B -> coalesced 1KB stores. Same per-element arithmetic as
    // before -> bit-identical MFMA inputs.
    {
        const int w = g0 >> 6;           // global wave id, 0..4095
        if (w < 4096) {
            const int lane = threadIdx.x & 63;
            const int tx = lane & 15;
            const int q  = lane >> 4;
            const int r16 = w >> 3;      // 0..511
            const int ktc = w & 7;       // 0..7
            const int row = r16 * 16 + tx;
            const float4 v0 = a[row * 64 + ktc * 8 + q * 2];
            const float4 v1 = a[row * 64 + ktc * 8 + q * 2 + 1];
            float e[8] = {v0.x, v0.y, v0.z, v0.w, v1.x, v1.y, v1.z, v1.w};
            short8 hs, ls;
            #pragma unroll
            for (int j = 0; j < 8; j++) {
                ushort h = f2bf(e[j]);
                ushort l = f2bf(e[j] - bf2f(h));
                hs[j] = (short)h;
                ls[j] = (short)l;
            }
            const size_t off = (size_t)(r16 * 8 + ktc) * 512 + lane * 8;
            *(short8*)&Ehi[off] = hs;
            *(short8*)&Elo[off] = ls;
        }
    }
    // M init
    for (int i = g0; i < N; i += gsz) M[i] = 0xFFFFFFFFFFFFFFFFull;
}

// ---------------- K2: symmetric split-bf16 MFMA + dual-sided masked argmin ----------------
// Barrier-free K-loop, liveness-shaved software pipeline:
//   - 32 fully-unrolled rt-steps (8 k-chunks x 4 rt)
//   - B frags (8/chunk, reused by all rt) double-buffered by chunk parity
//   - A frags in a 3-slot rolling window, loaded 2 steps ahead
//   - per step: issue loads -> sched_barrier(0) -> 12 MFMAs
// Peak live frags ~22 (88 VGPR) + 64 acc -> fits 256-reg cap at 2 waves/SIMD
// with NO spill (round 3's full depth-1 buffer spilled 17 regs -> 37 MB scratch).
// Per-acc order (hh,hl,lh per chunk, ascending chunks) identical to all prior
// revs -> bit-identical keys -> identical argmin indices.
__launch_bounds__(256, 2)
__global__ void argmin_sym(const ushort* __restrict__ Ehi, const ushort* __restrict__ Elo,
                           const int* __restrict__ host, const float* __restrict__ sq,
                           unsigned long long* __restrict__ M) {
    // XCD swizzle then decode linear tile id -> (ti, tj), ti <= tj
    const int b0 = blockIdx.x;
    const int b = (b0 & 7) * (NTRI / 8) + (b0 >> 3);
    int ti = (int)floor(64.5 - sqrt(64.5 * 64.5 - 2.0 * (double)b));
    while (triT(ti + 1) <= b) ti++;
    while (triT(ti) > b) ti--;
    const int tj = ti + (b - triT(ti));

    __shared__ float sqA_s[BI], sqB_s[BI];
    __shared__ int   hostB_s[BI];
    __shared__ float rowV[2 * BI]; __shared__ int rowI[2 * BI];
    __shared__ float colV[2 * BI]; __shared__ int colI[2 * BI];

    const int ib0 = ti * BI;
    const int jb0 = tj * BI;
    const int tid = threadIdx.x;
    const int lane = tid & 63;
    const int wave = tid >> 6;      // 0..3
    const int wrow = wave >> 1;     // 0..1
    const int wcol = wave & 1;      // 0..1
    const int tx = lane & 15;       // 0..15
    const int q  = lane >> 4;       // 0..3

    // epilogue scalars (consumed only after the pre-epilogue barrier)
    if (tid < BI) {
        sqA_s[tid] = sq[ib0 + tid];
        sqB_s[tid] = sq[jb0 + tid];
        hostB_s[tid] = host[jb0 + tid];
    }

    // hostA packed per rt: 4 bytes = hosts of rows (rt,reg) for this lane (host < 64)
    unsigned hostAp[4];
    #pragma unroll
    for (int rt = 0; rt < 4; rt++) {
        unsigned p = 0;
        #pragma unroll
        for (int reg = 0; reg < 4; reg++) {
            int hv = host[ib0 + wrow * 64 + rt * 16 + q * 4 + reg];
            p |= ((unsigned)hv & 0xFFu) << (8 * reg);
        }
        hostAp[rt] = p;
    }

    float4v acc[4][4];   // [rt][ct]
    #pragma unroll
    for (int rt = 0; rt < 4; rt++)
        #pragma unroll
        for (int ct = 0; ct < 4; ct++) acc[rt][ct] = (float4v)(0.0f);

    // frag-tile row16 bases for this wave's A rows / B cols
    const int pA = (ib0 >> 4) + wrow * 4;   // + rt
    const int pB = (jb0 >> 4) + wcol * 4;   // + ct
    const int lo8 = lane * 8;

    // pipeline registers (all indices compile-time after full unroll)
    short8 aH[3], aL[3];          // A rolling window, slot = step % 3
    short8 bhv[2][4], blv[2][4];  // B chunk double-buffer, parity = chunk & 1

    auto loadA = [&](int s) {     // s = global rt-step, compile-time constant
        const int k = s >> 2, rt = s & 3, sl = s % 3;
        const int o = ((pA + rt) * 8 + k) * 512 + lo8;
        aH[sl] = *(const short8*)&Ehi[o];
        aL[sl] = *(const short8*)&Elo[o];
    };
    auto loadB = [&](int k) {     // k = chunk, compile-time constant
        const int p = k & 1;
        #pragma unroll
        for (int ct = 0; ct < 4; ct++) {
            const int o = ((pB + ct) * 8 + k) * 512 + lo8;
            bhv[p][ct] = *(const short8*)&Ehi[o];
            blv[p][ct] = *(const short8*)&Elo[o];
        }
    };

    // prologue: B(0) + A(step 0,1) in flight
    loadB(0);
    loadA(0);
    loadA(1);

    #pragma unroll
    for (int s = 0; s < 32; s++) {
        const int k = s >> 2;     // chunk 0..7
        const int rt = s & 3;
        const int sl = s % 3;
        const int p = k & 1;
        if (rt == 0 && k < 7) loadB(k + 1);   // B prefetch, ~4 steps ahead
        if (s + 2 < 32) loadA(s + 2);         // A prefetch, 2 steps ahead
        __builtin_amdgcn_sched_barrier(0);    // pin loads above the MFMA cluster
        #pragma unroll
        for (int ct = 0; ct < 4; ct++)
            acc[rt][ct] = __builtin_amdgcn_mfma_f32_16x16x32_bf16(aH[sl], bhv[p][ct], acc[rt][ct], 0, 0, 0);
        #pragma unroll
        for (int ct = 0; ct < 4; ct++)
            acc[rt][ct] = __builtin_amdgcn_mfma_f32_16x16x32_bf16(aH[sl], blv[p][ct], acc[rt][ct], 0, 0, 0);
        #pragma unroll
        for (int ct = 0; ct < 4; ct++)
            acc[rt][ct] = __builtin_amdgcn_mfma_f32_16x16x32_bf16(aL[sl], bhv[p][ct], acc[rt][ct], 0, 0, 0);
    }

    // ---- epilogue: dual-sided argmin ----
    __syncthreads();   // orders the tid<128 sq/host staging before reads (only block barrier)

    // rows side: for each of this lane's 16 rows, min over its 4 ct entries, then over tx
    #pragma unroll
    for (int rt = 0; rt < 4; rt++) {
        unsigned hp = hostAp[rt];
        #pragma unroll
        for (int reg = 0; reg < 4; reg++) {
            int il = wrow * 64 + rt * 16 + q * 4 + reg;
            int ig = ib0 + il;
            int ha = (int)((hp >> (8 * reg)) & 0xFFu);
            float v = 3.0e38f; int ix = 0x7fffffff;
            #pragma unroll
            for (int ct = 0; ct < 4; ct++) {
                int jl = wcol * 64 + ct * 16 + tx;
                int jg = jb0 + jl;
                float key = sqB_s[jl] - 2.0f * acc[rt][ct][reg];
                bool masked = (hostB_s[jl] == ha) || (jg == ig);
                if (!masked && (key < v || (key == v && jg < ix))) { v = key; ix = jg; }
            }
            #pragma unroll
            for (int d = 1; d < 16; d <<= 1) {
                float ov = __shfl_xor(v, d);
                int   oi = __shfl_xor(ix, d);
                if (ov < v || (ov == v && oi < ix)) { v = ov; ix = oi; }
            }
            if (tx == 0) { rowV[il * 2 + wcol] = v; rowI[il * 2 + wcol] = ix; }
        }
    }

    // cols side (off-diagonal only): per lane's 4 cols, min over 16 row entries, then over q
    if (ti != tj) {
        #pragma unroll
        for (int ct = 0; ct < 4; ct++) {
            int jl = wcol * 64 + ct * 16 + tx;
            int hb = hostB_s[jl];
            float v = 3.0e38f; int ix = 0x7fffffff;
            #pragma unroll
            for (int rt = 0; rt < 4; rt++) {
                unsigned hp = hostAp[rt];
                #pragma unroll
                for (int reg = 0; reg < 4; reg++) {
                    int il = wrow * 64 + rt * 16 + q * 4 + reg;
                    int ig = ib0 + il;
                    bool masked = ((int)((hp >> (8 * reg)) & 0xFFu) == hb);
                    float key = sqA_s[il] - 2.0f * acc[rt][ct][reg];
                    if (!masked && (key < v || (key == v && ig < ix))) { v = key; ix = ig; }
                }
            }
            #pragma unroll
            for (int d = 16; d < 64; d <<= 1) {
                float ov = __shfl_xor(v, d);
                int   oi = __shfl_xor(ix, d);
                if (ov < v || (ov == v && oi < ix)) { v = ov; ix = oi; }
            }
            if (q == 0) { colV[jl * 2 + wrow] = v; colI[jl * 2 + wrow] = ix; }
        }
    }

    __syncthreads();
    if (tid < BI) {
        float v0 = rowV[tid * 2];     int x0 = rowI[tid * 2];
        float v1 = rowV[tid * 2 + 1]; int x1 = rowI[tid * 2 + 1];
        if (v1 < v0 || (v1 == v0 && x1 < x0)) { v0 = v1; x0 = x1; }
        atomicMin(&M[ib0 + tid], packKI(v0, x0));
        if (ti != tj) {
            float w0 = colV[tid * 2];     int y0 = colI[tid * 2];
            float w1 = colV[tid * 2 + 1]; int y1 = colI[tid * 2 + 1];
            if (w1 < w0 || (w1 == w0 && y1 < y0)) { w0 = w1; y0 = y1; }
            atomicMin(&M[jb0 + tid], packKI(w0, y0));
        }
    }
}

// ---------------- K3: extract index and gather e_an rows ----------------
__global__ void finalize_kernel(const unsigned long long* __restrict__ M,
                                const float* __restrict__ E, float* __restrict__ out_an) {
    int row = blockIdx.x;
    int t = threadIdx.x;   // 64
    int idx = (int)(unsigned)(M[row] & 0xFFFFFFFFull);
    float4 v = *(const float4*)&E[(size_t)idx * D + t * 4];
    *(float4*)&out_an[(size_t)row * D + t * 4] = v;
}

extern "C" void kernel_launch(void* const* d_in, const int* in_sizes, int n_in,
                              void* d_out, int out_size, void* d_ws, size_t ws_size,
                              hipStream_t stream) {
    const float* e_actv = (const float*)d_in[0];
    const float* e_ap   = (const float*)d_in[1];
    const int*   host   = (const int*)d_in[2];
    float* out = (float*)d_out;

    // workspace: M u64[N] | sq f32[N] | Ehi bf16[N*D] | Elo bf16[N*D]  (~8.3 MB)
    unsigned long long* M = (unsigned long long*)d_ws;
    float*  sq  = (float*)(M + N);
    ushort* Ehi = (ushort*)(sq + N);
    ushort* Elo = Ehi + (size_t)N * D;

    prep_kernel<<<1024, 256, 0, stream>>>(
        (const float4*)e_actv, (const float4*)e_ap, (float4*)out,
        sq, Ehi, Elo, M);
    argmin_sym<<<NTRI, 256, 0, stream>>>(Ehi, Elo, host, sq, M);
    finalize_kernel<<<N, 64, 0, stream>>>(M, e_actv, out + 2 * (size_t)N * D);
}

// Round 5
// 182.060 us; speedup vs baseline: 1.0618x; 1.0328x over previous
//
#include <hip/hip_runtime.h>
#include <hip/hip_bf16.h>
#include <cmath>
#include <cstddef>

#define N 8192
#define D 256
#define BIR 128                 // rows per block tile
#define BJC 64                  // cols per block tile
#define NBI (N / BIR)           // 64 row bands
#define NBLK 4160               // sum over ti of (128 - 2*ti) = ti*(129-ti) at 64

typedef __attribute__((ext_vector_type(8))) short short8;   // 8 bf16 = one MFMA A/B frag
typedef __attribute__((ext_vector_type(4))) float float4v;  // MFMA C/D frag

__device__ inline ushort f2bf(float x) {
    __hip_bfloat16 h = __float2bfloat16(x);
    return __builtin_bit_cast(ushort, h);
}
__device__ inline float bf2f(ushort u) {
    __hip_bfloat16 h = __builtin_bit_cast(__hip_bfloat16, u);
    return __bfloat162float(h);
}

// sortable pack: (monotone-uint(key) << 32) | idx  -> atomicMin == argmin, lowest-idx tie-break
__device__ inline unsigned long long packKI(float k, int idx) {
    unsigned u = __float_as_uint(k);
    u = (u & 0x80000000u) ? ~u : (u | 0x80000000u);
    return ((unsigned long long)u << 32) | (unsigned)idx;
}

// S(t) = blocks before row band t: t * (129 - t)
__device__ inline int bandS(int t) { return t * (129 - t); }

// ============================================================================
// Frag-tiled bf16 layout (unchanged): frag for (16-row group g, k-chunk k, lane)
// at ushort offset (g*8 + k)*512 + lane*8 -> wave frag load = uniform base +
// lane*16B: one coalesced 1 KB dwordx4.
// ============================================================================

// ---------------- K1: fused prep — M init, copies, sqnorm, frag-tiled bf16 hi/lo split ----
// grid MUST be 1024 x 256 (phase C uses exactly 4096 waves, one 16x32 tile each).
__global__ void prep_kernel(const float4* __restrict__ a, const float4* __restrict__ p,
                            float4* __restrict__ out, float* __restrict__ sq,
                            ushort* __restrict__ Ehi, ushort* __restrict__ Elo,
                            unsigned long long* __restrict__ M) {
    const int gsz = gridDim.x * blockDim.x;          // 262144, multiple of 64
    const int g0 = blockIdx.x * blockDim.x + threadIdx.x;
    const int total = N * D / 4;                     // 524288 float4

    // phase A: e_actv copy + per-row sqnorm (one row per wave per iter: 64 float4 = 1 row)
    for (int idx = g0; idx < total; idx += gsz) {
        float4 v = a[idx];
        out[idx] = v;
        float s = v.x * v.x + v.y * v.y + v.z * v.z + v.w * v.w;
        #pragma unroll
        for (int off = 32; off; off >>= 1) s += __shfl_down(s, off);
        if ((threadIdx.x & 63) == 0) sq[idx >> 6] = s;
    }
    // phase B: e_ap plain copy into second output slot
    for (int idx = g0; idx < total; idx += gsz) out[total + idx] = p[idx];

    // phase C: frag-tiled hi/lo split. One wave per (r16, ktc) tile of 16 rows x 32 k.
    {
        const int w = g0 >> 6;           // global wave id, 0..4095
        if (w < 4096) {
            const int lane = threadIdx.x & 63;
            const int tx = lane & 15;
            const int q  = lane >> 4;
            const int r16 = w >> 3;      // 0..511
            const int ktc = w & 7;       // 0..7
            const int row = r16 * 16 + tx;
            const float4 v0 = a[row * 64 + ktc * 8 + q * 2];
            const float4 v1 = a[row * 64 + ktc * 8 + q * 2 + 1];
            float e[8] = {v0.x, v0.y, v0.z, v0.w, v1.x, v1.y, v1.z, v1.w};
            short8 hs, ls;
            #pragma unroll
            for (int j = 0; j < 8; j++) {
                ushort h = f2bf(e[j]);
                ushort l = f2bf(e[j] - bf2f(h));
                hs[j] = (short)h;
                ls[j] = (short)l;
            }
            const size_t off = (size_t)(r16 * 8 + ktc) * 512 + lane * 8;
            *(short8*)&Ehi[off] = hs;
            *(short8*)&Elo[off] = ls;
        }
    }
    // M init
    for (int i = g0; i < N; i += gsz) M[i] = 0xFFFFFFFFFFFFFFFFull;
}

// ---------------- K2: 128x64 tiles, 4 waves of 64x32, chunk-double-buffered regs ----------
// Coverage: blocks (ti, tj) over 128-row bands x 64-col tiles with tj >= 2*ti.
// Every unordered pair {p<q} appears exactly once as an (i=p, j=q) element with
// jg > ig; elements with jg <= ig (diagonal-straddling tiles) are masked.
// MFMA dot is operand-order symmetric bitwise, and per-acc accumulation order
// (hh,hl,lh per chunk, chunks ascending) is unchanged -> keys bit-identical to
// all prior revs -> identical argmin indices.
// Register budget: 32 acc + 2x12 frags (96) + ~30 misc ~ 158 -> 3 waves/SIMD.
__launch_bounds__(256, 3)
__global__ void argmin_sym(const ushort* __restrict__ Ehi, const ushort* __restrict__ Elo,
                           const int* __restrict__ host, const float* __restrict__ sq,
                           unsigned long long* __restrict__ M) {
    // XCD swizzle (4160 = 8*520, bijective) then decode b -> (ti, tj), tj >= 2*ti
    const int b0 = blockIdx.x;
    const int b = (b0 & 7) * (NBLK / 8) + (b0 >> 3);
    int ti = (int)floor((129.0 - sqrt(129.0 * 129.0 - 4.0 * (double)b)) * 0.5);
    while (bandS(ti + 1) <= b) ti++;
    while (bandS(ti) > b) ti--;
    const int tj = 2 * ti + (b - bandS(ti));

    __shared__ float sqA_s[BIR];
    __shared__ float sqB_s[BJC];
    __shared__ int   hostB_s[BJC];
    __shared__ float rowV[2 * BIR]; __shared__ int rowI[2 * BIR];
    __shared__ float colV[2 * BJC]; __shared__ int colI[2 * BJC];

    const int ib0 = ti * BIR;
    const int jb0 = tj * BJC;
    const int tid = threadIdx.x;
    const int lane = tid & 63;
    const int wave = tid >> 6;      // 0..3
    const int wrow = wave >> 1;     // 0..1  (64-row half)
    const int wcol = wave & 1;      // 0..1  (32-col half)
    const int tx = lane & 15;       // 0..15
    const int q  = lane >> 4;       // 0..3

    // epilogue scalars (consumed only after the pre-epilogue barrier)
    if (tid < BIR) sqA_s[tid] = sq[ib0 + tid];
    if (tid < BJC) {
        sqB_s[tid] = sq[jb0 + tid];
        hostB_s[tid] = host[jb0 + tid];
    }

    // hostA packed per rt: 4 bytes = hosts of rows (rt,reg) for this lane (host < 64)
    unsigned hostAp[4];
    #pragma unroll
    for (int rt = 0; rt < 4; rt++) {
        unsigned p = 0;
        #pragma unroll
        for (int reg = 0; reg < 4; reg++) {
            int hv = host[ib0 + wrow * 64 + rt * 16 + q * 4 + reg];
            p |= ((unsigned)hv & 0xFFu) << (8 * reg);
        }
        hostAp[rt] = p;
    }

    float4v acc[4][2];   // [rt][ct] — 32 f32/lane
    #pragma unroll
    for (int rt = 0; rt < 4; rt++)
        #pragma unroll
        for (int ct = 0; ct < 2; ct++) acc[rt][ct] = (float4v)(0.0f);

    // frag-tile 16-row-group bases
    const int pA = (ib0 >> 4) + wrow * 4;   // + rt (0..3)
    const int pB = (jb0 >> 4) + wcol * 2;   // + ct (0..1)
    const int lo8 = lane * 8;

    // chunk-level double-buffered frag registers (slot = k & 1, compile-time)
    short8 aH[2][4], aL[2][4], bH[2][2], bL[2][2];

    auto loadChunk = [&](int k) {     // k compile-time constant
        const int s = k & 1;
        #pragma unroll
        for (int rt = 0; rt < 4; rt++) {
            const int o = ((pA + rt) * 8 + k) * 512 + lo8;
            aH[s][rt] = *(const short8*)&Ehi[o];
            aL[s][rt] = *(const short8*)&Elo[o];
        }
        #pragma unroll
        for (int ct = 0; ct < 2; ct++) {
            const int o = ((pB + ct) * 8 + k) * 512 + lo8;
            bH[s][ct] = *(const short8*)&Ehi[o];
            bL[s][ct] = *(const short8*)&Elo[o];
        }
    };

    // prologue: chunks 0 and 1 in flight (24 loads)
    loadChunk(0);
    loadChunk(1);

    #pragma unroll
    for (int k = 0; k < 8; k++) {
        const int s = k & 1;
        __builtin_amdgcn_sched_barrier(0);   // keep load batches above this chunk's MFMAs
        #pragma unroll
        for (int rt = 0; rt < 4; rt++)
            #pragma unroll
            for (int ct = 0; ct < 2; ct++)
                acc[rt][ct] = __builtin_amdgcn_mfma_f32_16x16x32_bf16(aH[s][rt], bH[s][ct], acc[rt][ct], 0, 0, 0);
        #pragma unroll
        for (int rt = 0; rt < 4; rt++)
            #pragma unroll
            for (int ct = 0; ct < 2; ct++)
                acc[rt][ct] = __builtin_amdgcn_mfma_f32_16x16x32_bf16(aH[s][rt], bL[s][ct], acc[rt][ct], 0, 0, 0);
        #pragma unroll
        for (int rt = 0; rt < 4; rt++)
            #pragma unroll
            for (int ct = 0; ct < 2; ct++)
                acc[rt][ct] = __builtin_amdgcn_mfma_f32_16x16x32_bf16(aL[s][rt], bH[s][ct], acc[rt][ct], 0, 0, 0);
        __builtin_amdgcn_sched_barrier(0);   // pin next load batch right here (no sinking)
        if (k + 2 < 8) loadChunk(k + 2);     // refill freed slot, ~1 full iter ahead of use
    }

    // ---- epilogue: dual-sided argmin ----
    __syncthreads();   // orders the sq/host staging before reads (only block barrier)

    // rows side: per lane's 16 rows, min over its 2 ct entries, then over tx
    #pragma unroll
    for (int rt = 0; rt < 4; rt++) {
        unsigned hp = hostAp[rt];
        #pragma unroll
        for (int reg = 0; reg < 4; reg++) {
            int il = wrow * 64 + rt * 16 + q * 4 + reg;
            int ig = ib0 + il;
            int ha = (int)((hp >> (8 * reg)) & 0xFFu);
            float v = 3.0e38f; int ix = 0x7fffffff;
            #pragma unroll
            for (int ct = 0; ct < 2; ct++) {
                int jl = wcol * 32 + ct * 16 + tx;
                int jg = jb0 + jl;
                float key = sqB_s[jl] - 2.0f * acc[rt][ct][reg];
                bool masked = (hostB_s[jl] == ha) || (jg <= ig);   // strict upper: i<j only
                if (!masked && (key < v || (key == v && jg < ix))) { v = key; ix = jg; }
            }
            #pragma unroll
            for (int d = 1; d < 16; d <<= 1) {
                float ov = __shfl_xor(v, d);
                int   oi = __shfl_xor(ix, d);
                if (ov < v || (ov == v && oi < ix)) { v = ov; ix = oi; }
            }
            if (tx == 0) { rowV[il * 2 + wcol] = v; rowI[il * 2 + wcol] = ix; }
        }
    }

    // cols side (always on): per lane's 2 cols, min over 16 row entries, then over q
    #pragma unroll
    for (int ct = 0; ct < 2; ct++) {
        int jl = wcol * 32 + ct * 16 + tx;
        int jg = jb0 + jl;
        int hb = hostB_s[jl];
        float v = 3.0e38f; int ix = 0x7fffffff;
        #pragma unroll
        for (int rt = 0; rt < 4; rt++) {
            unsigned hp = hostAp[rt];
            #pragma unroll
            for (int reg = 0; reg < 4; reg++) {
                int il = wrow * 64 + rt * 16 + q * 4 + reg;
                int ig = ib0 + il;
                bool masked = ((int)((hp >> (8 * reg)) & 0xFFu) == hb) || (ig >= jg);
                float key = sqA_s[il] - 2.0f * acc[rt][ct][reg];
                if (!masked && (key < v || (key == v && ig < ix))) { v = key; ix = ig; }
            }
        }
        #pragma unroll
        for (int d = 16; d < 64; d <<= 1) {
            float ov = __shfl_xor(v, d);
            int   oi = __shfl_xor(ix, d);
            if (ov < v || (ov == v && oi < ix)) { v = ov; ix = oi; }
        }
        if (q == 0) { colV[jl * 2 + wrow] = v; colI[jl * 2 + wrow] = ix; }
    }

    __syncthreads();
    if (tid < BIR) {
        float v0 = rowV[tid * 2];     int x0 = rowI[tid * 2];
        float v1 = rowV[tid * 2 + 1]; int x1 = rowI[tid * 2 + 1];
        if (v1 < v0 || (v1 == v0 && x1 < x0)) { v0 = v1; x0 = x1; }
        atomicMin(&M[ib0 + tid], packKI(v0, x0));
    }
    if (tid < BJC) {
        float w0 = colV[tid * 2];     int y0 = colI[tid * 2];
        float w1 = colV[tid * 2 + 1]; int y1 = colI[tid * 2 + 1];
        if (w1 < w0 || (w1 == w0 && y1 < y0)) { w0 = w1; y0 = y1; }
        atomicMin(&M[jb0 + tid], packKI(w0, y0));
    }
}

// ---------------- K3: extract index and gather e_an rows ----------------
__global__ void finalize_kernel(const unsigned long long* __restrict__ M,
                                const float* __restrict__ E, float* __restrict__ out_an) {
    int row = blockIdx.x;
    int t = threadIdx.x;   // 64
    int idx = (int)(unsigned)(M[row] & 0xFFFFFFFFull);
    float4 v = *(const float4*)&E[(size_t)idx * D + t * 4];
    *(float4*)&out_an[(size_t)row * D + t * 4] = v;
}

extern "C" void kernel_launch(void* const* d_in, const int* in_sizes, int n_in,
                              void* d_out, int out_size, void* d_ws, size_t ws_size,
                              hipStream_t stream) {
    const float* e_actv = (const float*)d_in[0];
    const float* e_ap   = (const float*)d_in[1];
    const int*   host   = (const int*)d_in[2];
    float* out = (float*)d_out;

    // workspace: M u64[N] | sq f32[N] | Ehi bf16[N*D] | Elo bf16[N*D]  (~8.3 MB)
    unsigned long long* M = (unsigned long long*)d_ws;
    float*  sq  = (float*)(M + N);
    ushort* Ehi = (ushort*)(sq + N);
    ushort* Elo = Ehi + (size_t)N * D;

    prep_kernel<<<1024, 256, 0, stream>>>(
        (const float4*)e_actv, (const float4*)e_ap, (float4*)out,
        sq, Ehi, Elo, M);
    argmin_sym<<<NBLK, 256, 0, stream>>>(Ehi, Elo, host, sq, M);
    finalize_kernel<<<N, 64, 0, stream>>>(M, e_actv, out + 2 * (size_t)N * D);
}